// Round 17
// baseline (1089.778 us; speedup 1.0000x reference)
//
#include <hip/hip_runtime.h>
#include <hip/hip_bf16.h>
#include <stdint.h>

#define LL 128
#define BB 64
#define VV 10000
#define EE 512
#define HH 512
#define G3 1536
#define MROWS 8192      // L*B
#define DM 8064         // (L-2)*B
#define D2H 1024
#define NPAD 10112      // 79*128
#define FP 16           // flag padding (ints) -> one 64B line per producer
#define NTILE_M 63
#define NTILE_N 79
#define DECQ (NTILE_M * NTILE_N)
#define DECB 224        // decoder worker blocks

typedef __bf16 bf16x8 __attribute__((ext_vector_type(8)));
typedef float f32x4 __attribute__((ext_vector_type(4)));
typedef int i32x4 __attribute__((ext_vector_type(4)));
typedef unsigned int u32x4 __attribute__((ext_vector_type(4)));
typedef unsigned int u32x2 __attribute__((ext_vector_type(2)));
typedef unsigned short u16;
typedef unsigned long long u64;

static __device__ __forceinline__ float bf2f(u16 u) {
  unsigned int x = ((unsigned int)u) << 16;
  return __builtin_bit_cast(float, x);
}
static __device__ __forceinline__ u16 f2bf(float f) {
  unsigned int x = __builtin_bit_cast(unsigned int, f);
  unsigned int r = x + 0x7FFFu + ((x >> 16) & 1u);
  return (u16)(r >> 16);
}
static __device__ __forceinline__ signed char q8(float v) {
  float r = fminf(fmaxf(rintf(v), -127.f), 127.f);
  return (signed char)(int)r;
}

// device-coherent (L1+L2-bypassing, visible at L3) ops
static __device__ __forceinline__ void cstore16(void* p, u32x4 v) {
  asm volatile("global_store_dwordx4 %0, %1, off sc0 sc1" :: "v"(p), "v"(v) : "memory");
}
static __device__ __forceinline__ void cstore8(void* p, u64 v) {
  u32x2 d = __builtin_bit_cast(u32x2, v);
  asm volatile("global_store_dwordx2 %0, %1, off sc0 sc1" :: "v"(p), "v"(d) : "memory");
}
static __device__ __forceinline__ void flagstore4(void* p, int v) {
  asm volatile("global_store_dword %0, %1, off sc0 sc1" :: "v"(p), "v"(v) : "memory");
}
static __device__ __forceinline__ int flagload4(const void* p) {
  int v;
  asm volatile("global_load_dword %0, %1, off sc0 sc1\n\ts_waitcnt vmcnt(0)"
               : "=v"(v) : "v"(p) : "memory");
  return v;
}
// async global->LDS, 16B per lane
static __device__ __forceinline__ void gload_lds16(const void* g, void* s) {
  __builtin_amdgcn_global_load_lds(
      (const __attribute__((address_space(1))) unsigned int*)g,
      (__attribute__((address_space(3))) unsigned int*)s, 16, 0, 0);
}

// ---------------- fused prep: quant_w + embed + weight casts ----------------
// grid partitioned by blockIdx.x:
//   [0, VV)              : decW row quantization
//   [VV, VV+4096)        : embedding gather (2 rows/block)
//   [VV+4096, VV+7168)   : 4 weight-tensor casts (768 blocks each)
__global__ __launch_bounds__(256) void k_prep(
    const float* __restrict__ decW, signed char* __restrict__ decWq,
    float* __restrict__ wscale,
    const int* __restrict__ seq, const float* __restrict__ emb,
    u16* __restrict__ xb,
    const float* __restrict__ Whhf, const float* __restrict__ Whhb,
    const float* __restrict__ Wihf, const float* __restrict__ Wihb,
    u16* __restrict__ Whh_bf, u16* __restrict__ Wih_bf)
{
  __shared__ float red[4];
  __shared__ float s_inv;
  const int bid = blockIdx.x;
  const int tid = threadIdx.x;

  if (bid < VV) {
    const int v = bid;
    const int l = tid & 63, w = tid >> 6;
    float4 x = *(const float4*)(decW + (long)v * 1024 + tid * 4);
    float m = fmaxf(fmaxf(fabsf(x.x), fabsf(x.y)), fmaxf(fabsf(x.z), fabsf(x.w)));
#pragma unroll
    for (int off = 32; off; off >>= 1) m = fmaxf(m, __shfl_xor(m, off));
    if (l == 0) red[w] = m;
    __syncthreads();
    if (tid == 0) {
      float mm = fmaxf(fmaxf(red[0], red[1]), fmaxf(red[2], red[3]));
      mm = fmaxf(mm, 1e-12f);
      s_inv = 127.f / mm;
      wscale[v] = mm / (127.f * 127.f);
    }
    __syncthreads();
    float inv = s_inv;
    char4 o;
    o.x = q8(x.x * inv); o.y = q8(x.y * inv); o.z = q8(x.z * inv); o.w = q8(x.w * inv);
    *(char4*)(decWq + (long)v * 1024 + tid * 4) = o;
  } else if (bid < VV + 4096) {
    int rb = (bid - VV) * 2 + (tid >> 7);   // row in [0, 8192)
    int t = tid & 127;
    int v = seq[rb];
    float4 val = ((const float4*)(emb + (long)v * EE))[t];
    ushort4 o;
    o.x = f2bf(val.x); o.y = f2bf(val.y); o.z = f2bf(val.z); o.w = f2bf(val.w);
    ((ushort4*)(xb + (long)rb * EE))[t] = o;
  } else {
    int c = bid - VV - 4096;                // [0, 3072)
    int tensor = c / 768;
    int i = (c % 768) * 256 + tid;          // < 196608
    const float4* s; ushort4* d;
    switch (tensor) {
      case 0: s = (const float4*)Whhf; d = (ushort4*)Whh_bf; break;
      case 1: s = (const float4*)Whhb; d = (ushort4*)(Whh_bf + G3 * HH); break;
      case 2: s = (const float4*)Wihf; d = (ushort4*)Wih_bf; break;
      default: s = (const float4*)Wihb; d = (ushort4*)(Wih_bf + G3 * EE); break;
    }
    float4 v = s[i];
    ushort4 o;
    o.x = f2bf(v.x); o.y = f2bf(v.y); o.z = f2bf(v.z); o.w = f2bf(v.w);
    d[i] = o;
  }
}

// ---------------- gx GEMM (both directions, blockIdx.z selects) -------------
__global__ __launch_bounds__(256) void k_gemm_gx(
    const u16* __restrict__ A, const u16* __restrict__ W0, const u16* __restrict__ W1,
    const float* __restrict__ b0, const float* __restrict__ b1, u16* __restrict__ C)
{
  __shared__ char smem[32768];
  const int tid = threadIdx.x;
  const int l = tid & 63;
  const int w = tid >> 6;
  const int wr = w >> 1, wc = w & 1;
  const long tM = (long)blockIdx.x * 128;
  const long tN = (long)blockIdx.y * 128;
  const int z = blockIdx.z;
  const u16* B = z ? W1 : W0;
  const float* bias = z ? b1 : b0;
  u16* Cz = C + (size_t)z * MROWS * G3;

  f32x4 acc[4][4];
#pragma unroll
  for (int m = 0; m < 4; m++)
#pragma unroll
    for (int n = 0; n < 4; n++) acc[m][n] = {0.f, 0.f, 0.f, 0.f};

  for (int kt = 0; kt < 8; ++kt) {
    const int k0 = kt << 6;
#pragma unroll
    for (int i = 0; i < 4; i++) {
      int cchunk = w * 4 + i;
      int c = cchunk * 64 + l;
      int row = c >> 3, k8 = c & 7;
      gload_lds16(A + (tM + row) * EE + k0 + k8 * 8, smem + cchunk * 1024);
      gload_lds16(B + (tN + row) * EE + k0 + k8 * 8, smem + 16384 + cchunk * 1024);
    }
    __syncthreads();
#pragma unroll
    for (int kk = 0; kk < 2; kk++) {
      const int kb = kk * 64 + ((l >> 4) * 16);
      bf16x8 af[4], bfr[4];
#pragma unroll
      for (int m = 0; m < 4; m++) {
        int ra = wr * 64 + m * 16 + (l & 15);
        af[m] = *(const bf16x8*)(smem + ra * 128 + kb);
      }
#pragma unroll
      for (int n = 0; n < 4; n++) {
        int rb2 = wc * 64 + n * 16 + (l & 15);
        bfr[n] = *(const bf16x8*)(smem + 16384 + rb2 * 128 + kb);
      }
#pragma unroll
      for (int m = 0; m < 4; m++)
#pragma unroll
        for (int n = 0; n < 4; n++)
          acc[m][n] = __builtin_amdgcn_mfma_f32_16x16x32_bf16(af[m], bfr[n], acc[m][n], 0, 0, 0);
    }
    __syncthreads();
  }
#pragma unroll
  for (int n = 0; n < 4; n++) {
    long col = tN + wc * 64 + n * 16 + (l & 15);
    float bv = bias[col];
#pragma unroll
    for (int m = 0; m < 4; m++) {
      long row = tM + wr * 64 + m * 16 + ((l >> 4) * 4);
#pragma unroll
      for (int r = 0; r < 4; r++)
        Cz[(row + r) * G3 + col] = f2bf(acc[m][n][r] + bv);
    }
  }
}

// ================= fused GRU + persistent decoder + lsm =================
// Blocks 0..31: GRU. Blocks 32..255: decoder workers (R15-proven body).
// After decode queue drains each decoder block does ONE release-bump of
// blocks_done; lsm phase waits blocks_done==DECB with an acquire load
// (L2 writeback/invalidate amortized to once per block), then plain tickets.

static __device__ void gru_body(
    int blk, int dir, int tid, char* lds,
    const u16* __restrict__ Whh_all,
    const float* __restrict__ bhh_f, const float* __restrict__ bhh_b,
    const u16* __restrict__ gx_all, u16* __restrict__ hsteps,
    signed char* __restrict__ catq, int* __restrict__ bar16)
{
  const int l = tid & 63, w = tid >> 6;
  const u16* Whh = Whh_all + (long)dir * G3 * HH;
  const float* bhh = dir ? bhh_b : bhh_f;
  const u16* gx = gx_all + (long)dir * MROWS * G3;

  char* Wl = lds;
  u16 (*hstage)[32] = (u16(*)[32])(lds + 96 * 1024);
  signed char (*hstageq)[32] = (signed char(*)[32])(lds + 96 * 1024 + 4096);

  for (int c = tid; c < 6144; c += 256) {
    int lr = c >> 6;
    int k8 = c & 63;
    int gr = (lr >> 5) * HH + blk * 32 + (lr & 31);
    uint4 v = *(const uint4*)(Whh + (long)gr * HH + k8 * 8);
    *(uint4*)(Wl + lr * 1024 + ((k8 * 16) ^ ((lr & 7) << 4))) = v;
  }
  float bh[6];
#pragma unroll
  for (int n = 0; n < 6; n++) {
    int c = n * 16 + (l & 15);
    bh[n] = bhh[(c >> 5) * HH + blk * 32 + (c & 31)];
  }
  float hreg[4][2] = {};
  __syncthreads();

  const int lrow = w * 16 + ((l >> 4) * 4);
  const int srow = tid >> 2, schunk = tid & 3;

  u16 gxn[3][4][2];
  {
    const int lpos0 = dir ? (LL - 1) : 0;
#pragma unroll
    for (int r = 0; r < 4; r++) {
      const u16* gxr = gx + ((long)lpos0 * BB + (lrow + r)) * G3 + blk * 32;
#pragma unroll
      for (int g = 0; g < 3; g++)
#pragma unroll
        for (int p = 0; p < 2; p++)
          gxn[g][r][p] = gxr[g * HH + p * 16 + (l & 15)];
    }
  }

  for (int t = 0; t < LL; ++t) {
    const int lpos = dir ? (LL - 1 - t) : t;
    const u16* hsrc = hsteps + ((size_t)t * 2 + dir) * BB * HH;

    u16 gxv[3][4][2];
#pragma unroll
    for (int g = 0; g < 3; g++)
#pragma unroll
      for (int r = 0; r < 4; r++)
#pragma unroll
        for (int p = 0; p < 2; p++) gxv[g][r][p] = gxn[g][r][p];

    bf16x8 af[16];
    {
      const u16* hrow = hsrc + (w * 16 + (l & 15)) * HH + ((l >> 4) * 8);
#pragma unroll
      for (int kc = 0; kc < 16; kc++) af[kc] = *(const bf16x8*)(hrow + kc * 32);
    }

    f32x4 acc[6];
#pragma unroll
    for (int n = 0; n < 6; n++) acc[n] = {0.f, 0.f, 0.f, 0.f};
#pragma unroll
    for (int kc = 0; kc < 16; kc++) {
      const int kb = kc * 64 + ((l >> 4) * 16);
#pragma unroll
      for (int n = 0; n < 6; n++) {
        int lr = n * 16 + (l & 15);
        bf16x8 bfr = *(const bf16x8*)(Wl + lr * 1024 + (kb ^ ((l & 7) << 4)));
        acc[n] = __builtin_amdgcn_mfma_f32_16x16x32_bf16(af[kc], bfr, acc[n], 0, 0, 0);
      }
    }

#pragma unroll
    for (int r = 0; r < 4; r++) {
#pragma unroll
      for (int p = 0; p < 2; p++) {
        float ghr = acc[0 + p][r] + bh[0 + p];
        float ghz = acc[2 + p][r] + bh[2 + p];
        float ghn = acc[4 + p][r] + bh[4 + p];
        float xr = bf2f(gxv[0][r][p]);
        float xz = bf2f(gxv[1][r][p]);
        float xn = bf2f(gxv[2][r][p]);
        float ar = fminf(fmaxf(xr + ghr, -30.f), 30.f);
        float az = fminf(fmaxf(xz + ghz, -30.f), 30.f);
        float rg = 1.f / (1.f + __expf(-ar));
        float zg = 1.f / (1.f + __expf(-az));
        float an = fminf(fmaxf(xn + rg * ghn, -30.f), 30.f);
        float e2 = __expf(-2.f * an);
        float ng = (1.f - e2) / (1.f + e2);
        float hn = (1.f - zg) * ng + zg * hreg[r][p];
        hreg[r][p] = hn;
        hstage[lrow + r][p * 16 + (l & 15)] = f2bf(hn);
        hstageq[lrow + r][p * 16 + (l & 15)] = q8(hn * 127.f);
      }
    }
    __syncthreads();

    u32x4 hv = *(const u32x4*)&hstage[srow][schunk * 8];
    u64 hq = *(const u64*)&hstageq[srow][schunk * 8];
    if (t < LL - 1)
      cstore16(hsteps + ((size_t)(t + 1) * 2 + dir) * BB * HH + srow * HH + blk * 32 + schunk * 8, hv);
    if (dir == 0) {
      if (lpos < LL - 2)
        cstore8(catq + ((long)lpos * BB + srow) * D2H + blk * 32 + schunk * 8, hq);
    } else {
      if (lpos >= 2)
        cstore8(catq + ((long)(lpos - 2) * BB + srow) * D2H + HH + blk * 32 + schunk * 8, hq);
    }
    if (t < LL - 1) {
      asm volatile("s_waitcnt vmcnt(0)" ::: "memory");
      __syncthreads();
      if (tid == 0)
        flagstore4(&bar16[((dir * LL + t) * 16 + blk) * FP], 1);
      {
        const int lposn = dir ? (LL - 2 - t) : (t + 1);
#pragma unroll
        for (int r = 0; r < 4; r++) {
          const u16* gxr = gx + ((long)lposn * BB + (lrow + r)) * G3 + blk * 32;
#pragma unroll
          for (int g = 0; g < 3; g++)
#pragma unroll
            for (int p = 0; p < 2; p++)
              gxn[g][r][p] = gxr[g * HH + p * 16 + (l & 15)];
        }
      }
      const int* flg = bar16 + (dir * LL + t) * 16 * FP;
      for (;;) {
        int v = 1;
        if (l < 16) v = flagload4(&flg[l * FP]);
        if (__all(v != 0)) break;
      }
      __builtin_amdgcn_sched_barrier(0);
    }
  }
}

static __device__ void dec_body(
    int tid, char* smem, int* tk_sh,
    const signed char* __restrict__ A, const signed char* __restrict__ B,
    const float* __restrict__ wscale, const float* __restrict__ bias,
    void* __restrict__ Cv, int outbf,
    int* __restrict__ ticket, const int* __restrict__ bar16,
    int* __restrict__ blocks_done)
{
  const int l = tid & 63;
  const int w = tid >> 6;
  const int wr = w >> 1, wc = w & 1;

  for (;;) {
    if (tid == 0)
      *tk_sh = __hip_atomic_fetch_add(ticket, 1, __ATOMIC_RELAXED, __HIP_MEMORY_SCOPE_AGENT);
    __syncthreads();
    const int n = *tk_sh;
    __syncthreads();
    if (n >= DECQ) {
      // queue drained: one release per block makes all its cached logits
      // stores visible at device scope (L2 writeback), then signal.
      asm volatile("s_waitcnt vmcnt(0)" ::: "memory");
      __syncthreads();
      if (tid == 0)
        __hip_atomic_fetch_add(blocks_done, 1, __ATOMIC_RELEASE, __HIP_MEMORY_SCOPE_AGENT);
      return;
    }
    const int k = n / NTILE_N, j = n % NTILE_N;
    const int mi = (k & 1) ? (31 + ((k + 1) >> 1)) : (31 - (k >> 1));
    const long tM = (long)mi * 128;
    const long tN = (long)j * 128;

    // readiness: fwd flag t=2mi+1, bwd flag t=125-2mi (cumulative visibility)
    {
      const int tf = 2 * mi + 1;
      const int tb = 125 - 2 * mi;
      const int* fp = (l < 16)
          ? bar16 + ((0 * LL + tf) * 16 + l) * FP
          : bar16 + ((1 * LL + tb) * 16 + (l & 15)) * FP;
      for (;;) {
        int v = 1;
        if (l < 32) v = flagload4(fp);
        if (__all(v != 0)) break;
      }
    }

    i32x4 acc[4][4];
#pragma unroll
    for (int m = 0; m < 4; m++)
#pragma unroll
      for (int nn = 0; nn < 4; nn++) acc[m][nn] = {0, 0, 0, 0};

    for (int kt = 0; kt < 8; ++kt) {
      const int k0 = kt << 7;
#pragma unroll
      for (int i = 0; i < 4; i++) {
        int jj = w * 4 + i;
        int row = jj * 8 + (l >> 3);
        int k16 = l & 7;
        gload_lds16(A + (tM + row) * 1024 + k0 + k16 * 16, smem + jj * 1024);
        gload_lds16(B + (tN + row) * 1024 + k0 + k16 * 16, smem + 16384 + jj * 1024);
      }
      __syncthreads();
#pragma unroll
      for (int ks = 0; ks < 2; ks++) {
        const int kb = ks * 64 + ((l >> 4) * 16);
        i32x4 af[4], bfr[4];
#pragma unroll
        for (int m = 0; m < 4; m++) {
          int ra = wr * 64 + m * 16 + (l & 15);
          af[m] = *(const i32x4*)(smem + ra * 128 + kb);
        }
#pragma unroll
        for (int nn = 0; nn < 4; nn++) {
          int rb2 = wc * 64 + nn * 16 + (l & 15);
          bfr[nn] = *(const i32x4*)(smem + 16384 + rb2 * 128 + kb);
        }
#pragma unroll
        for (int m = 0; m < 4; m++)
#pragma unroll
          for (int nn = 0; nn < 4; nn++)
            acc[m][nn] = __builtin_amdgcn_mfma_i32_16x16x64_i8(af[m], bfr[nn], acc[m][nn], 0, 0, 0);
      }
      __syncthreads();
    }
    // epilogue: plain cached stores (R15-proven); visibility via the single
    // release at queue-drain time.
#pragma unroll
    for (int nn = 0; nn < 4; nn++) {
      long col = tN + wc * 64 + nn * 16 + (l & 15);
      if (col < VV) {
        float sc = wscale[col];
        float bv = bias[col];
#pragma unroll
        for (int m = 0; m < 4; m++) {
          long row = tM + wr * 64 + m * 16 + ((l >> 4) * 4);
#pragma unroll
          for (int r = 0; r < 4; r++) {
            float vv = (float)acc[m][nn][r] * sc + bv;
            if (outbf) ((u16*)Cv)[(row + r) * NPAD + col] = f2bf(vv);
            else       ((float*)Cv)[(row + r) * VV + col] = vv;
          }
        }
      }
    }
    __syncthreads();
  }
}

// lsm phase: wait all decoder blocks released, then plain row tickets.
static __device__ void lsm_phase(
    int tid, char* lds, int* tk_sh,
    const u16* __restrict__ lg, float* __restrict__ out,
    int* __restrict__ ticket_lsm, int* __restrict__ blocks_done)
{
  if (tid == 0) {
    while (__hip_atomic_load(blocks_done, __ATOMIC_ACQUIRE, __HIP_MEMORY_SCOPE_AGENT) < DECB)
      __builtin_amdgcn_s_sleep(8);
  }
  __syncthreads();   // all threads pass only after acquire observed DECB

  float* red = (float*)lds;
  const int l = tid & 63, w = tid >> 6;
  for (;;) {
    if (tid == 0)
      *tk_sh = __hip_atomic_fetch_add(ticket_lsm, 1, __ATOMIC_RELAXED, __HIP_MEMORY_SCOPE_AGENT);
    __syncthreads();
    const int n = *tk_sh;
    __syncthreads();
    if (n >= DM) return;

    const long row = n;
    const u16* p = lg + row * NPAD;
    float* q = out + row * VV;

    float v[5][8];
    float m = -1e30f;
#pragma unroll
    for (int j = 0; j < 5; j++) {
      int idx8 = j * 256 + tid;
      if (idx8 < 1250) {
        u32x4 u = *(const u32x4*)(p + idx8 * 8);
#pragma unroll
        for (int e = 0; e < 4; e++) {
          v[j][2 * e]     = bf2f((u16)(u[e] & 0xffffu));
          v[j][2 * e + 1] = bf2f((u16)(u[e] >> 16));
        }
#pragma unroll
        for (int e = 0; e < 8; e++) m = fmaxf(m, v[j][e]);
      }
    }
#pragma unroll
    for (int off = 32; off; off >>= 1) m = fmaxf(m, __shfl_xor(m, off));
    if (l == 0) red[w] = m;
    __syncthreads();
    m = fmaxf(fmaxf(red[0], red[1]), fmaxf(red[2], red[3]));

    float s = 0.f;
#pragma unroll
    for (int j = 0; j < 5; j++) {
      int idx8 = j * 256 + tid;
      if (idx8 < 1250) {
#pragma unroll
        for (int e = 0; e < 8; e++) s += __expf(v[j][e] - m);
      }
    }
#pragma unroll
    for (int off = 32; off; off >>= 1) s += __shfl_xor(s, off);
    if (l == 0) red[4 + w] = s;
    __syncthreads();
    s = red[4] + red[5] + red[6] + red[7];
    float lse = m + logf(s);

#pragma unroll
    for (int j = 0; j < 5; j++) {
      int idx8 = j * 256 + tid;
      if (idx8 < 1250) {
        float4 a, b;
        a.x = v[j][0] - lse; a.y = v[j][1] - lse; a.z = v[j][2] - lse; a.w = v[j][3] - lse;
        b.x = v[j][4] - lse; b.y = v[j][5] - lse; b.z = v[j][6] - lse; b.w = v[j][7] - lse;
        *(float4*)(q + idx8 * 8) = a;
        *(float4*)(q + idx8 * 8 + 4) = b;
      }
    }
    __syncthreads();
  }
}

__global__ __launch_bounds__(256) void k_fused(
    const u16* __restrict__ Whh_all,
    const float* __restrict__ bhh_f, const float* __restrict__ bhh_b,
    const u16* __restrict__ gx_all, u16* __restrict__ hsteps,
    signed char* __restrict__ catq, int* __restrict__ bar16,
    const signed char* __restrict__ decWq, const float* __restrict__ wscale,
    const float* __restrict__ decb, void* __restrict__ Cv, int outbf,
    int* __restrict__ ticket, float* __restrict__ dout)
{
  __shared__ __align__(16) char lds[104448];
  __shared__ int tk_sh;
  const int bid = blockIdx.x;
  const int tid = threadIdx.x;
  if (bid < 32) {
    gru_body(bid >> 1, bid & 1, tid, lds, Whh_all, bhh_f, bhh_b, gx_all,
             hsteps, catq, bar16);
  } else {
    dec_body(tid, lds, &tk_sh, catq, decWq, wscale, decb, Cv, outbf,
             ticket, bar16, ticket + 24);
  }
  if (outbf)
    lsm_phase(tid, lds, &tk_sh, (const u16*)Cv, dout, ticket + 16, ticket + 24);
}

// ---------------- log-softmax, f32 in-place (fallback) ----------------
__global__ __launch_bounds__(256) void k_lsm(float* __restrict__ out) {
  const long row = blockIdx.x;
  float* p = out + row * VV;
  const int tid = threadIdx.x;
  const int l = tid & 63, w = tid >> 6;
  __shared__ float red[8];

  float4 v[10];
  float m = -1e30f;
#pragma unroll
  for (int j = 0; j < 10; j++) {
    int idx = j * 256 + tid;
    if (idx < 2500) {
      v[j] = *(float4*)(p + idx * 4);
      m = fmaxf(m, fmaxf(fmaxf(v[j].x, v[j].y), fmaxf(v[j].z, v[j].w)));
    }
  }
#pragma unroll
  for (int off = 32; off; off >>= 1) m = fmaxf(m, __shfl_xor(m, off));
  if (l == 0) red[w] = m;
  __syncthreads();
  m = fmaxf(fmaxf(red[0], red[1]), fmaxf(red[2], red[3]));

  float s = 0.f;
#pragma unroll
  for (int j = 0; j < 10; j++) {
    int idx = j * 256 + tid;
    if (idx < 2500) {
      s += __expf(v[j].x - m) + __expf(v[j].y - m) + __expf(v[j].z - m) + __expf(v[j].w - m);
    }
  }
#pragma unroll
  for (int off = 32; off; off >>= 1) s += __shfl_xor(s, off);
  if (l == 0) red[4 + w] = s;
  __syncthreads();
  s = red[4] + red[5] + red[6] + red[7];
  float lse = m + logf(s);

#pragma unroll
  for (int j = 0; j < 10; j++) {
    int idx = j * 256 + tid;
    if (idx < 2500) {
      float4 o;
      o.x = v[j].x - lse; o.y = v[j].y - lse; o.z = v[j].z - lse; o.w = v[j].w - lse;
      *(float4*)(p + idx * 4) = o;
    }
  }
}

// ---------------- launch ----------------
extern "C" void kernel_launch(void* const* d_in, const int* in_sizes, int n_in,
                              void* d_out, int out_size, void* d_ws, size_t ws_size,
                              hipStream_t stream) {
  const int*   seq  = (const int*)d_in[0];
  const float* emb  = (const float*)d_in[2];
  const float* Wihf = (const float*)d_in[3];
  const float* Whhf = (const float*)d_in[4];
  const float* bihf = (const float*)d_in[5];
  const float* bhhf = (const float*)d_in[6];
  const float* Wihb = (const float*)d_in[7];
  const float* Whhb = (const float*)d_in[8];
  const float* bihb = (const float*)d_in[9];
  const float* bhhb = (const float*)d_in[10];
  const float* decW = (const float*)d_in[11];
  const float* decb = (const float*)d_in[12];

  char* ws = (char*)d_ws;
  size_t off = 0;
  u16* Whh_bf = (u16*)(ws + off); off += (size_t)2 * G3 * HH * 2;
  u16* Wih_bf = (u16*)(ws + off); off += (size_t)2 * G3 * EE * 2;
  signed char* decWq = (signed char*)(ws + off); off += (size_t)NPAD * 1024;
  float* wscale = (float*)(ws + off); off += (size_t)NPAD * 4;
  u16* xb = (u16*)(ws + off); off += (size_t)MROWS * EE * 2;
  u16* gxb = (u16*)(ws + off); off += (size_t)2 * MROWS * G3 * 2;
  signed char* catq = (signed char*)(ws + off); off += (size_t)DM * D2H;
  u16* hsteps = (u16*)(ws + off); off += (size_t)(LL + 1) * 2 * BB * HH * 2;
  int* bar16 = (int*)(ws + off); off += (size_t)2 * LL * 16 * FP * 4;    // 2M
  int* ticket = (int*)(ws + off); off += 32 * 4;   // [0]=dec [16]=lsm [24]=done
  u16* logitsb = (u16*)(ws + off);
  const size_t logits_bytes = (size_t)DM * NPAD * 2;                     // 163M
  const bool use_bf16_logits = (ws_size >= off + logits_bytes);

  (void)hipMemsetAsync(hsteps, 0, (size_t)2 * BB * HH * 2, stream);
  (void)hipMemsetAsync(bar16, 0, (size_t)2 * LL * 16 * FP * 4 + 32 * 4, stream);

  k_prep<<<dim3(VV + 4096 + 3072), 256, 0, stream>>>(
      decW, decWq, wscale, seq, emb, xb,
      Whhf, Whhb, Wihf, Wihb, Whh_bf, Wih_bf);

  k_gemm_gx<<<dim3(64, 12, 2), 256, 0, stream>>>(xb, Wih_bf, Wih_bf + G3 * EE,
                                                 bihf, bihb, gxb);

  void* Cv = use_bf16_logits ? (void*)logitsb : (void*)d_out;
  k_fused<<<dim3(256), 256, 0, stream>>>(Whh_bf, bhhf, bhhb, gxb, hsteps, catq,
                                         bar16, decWq, wscale, decb, Cv,
                                         use_bf16_logits ? 1 : 0, ticket,
                                         (float*)d_out);

  if (!use_bf16_logits) k_lsm<<<DM, 256, 0, stream>>>((float*)d_out);
}

// Round 18
// 978.384 us; speedup vs baseline: 1.1139x; 1.1139x over previous
//
#include <hip/hip_runtime.h>
#include <hip/hip_bf16.h>
#include <stdint.h>

#define LL 128
#define BB 64
#define VV 10000
#define EE 512
#define HH 512
#define G3 1536
#define MROWS 8192      // L*B
#define DM 8064         // (L-2)*B
#define D2H 1024
#define NPAD 10112      // 79*128
#define FP 16           // flag padding (ints) -> one 64B line per producer
#define NTILE_M 63
#define NTILE_N 79
#define DECQ (NTILE_M * NTILE_N)

typedef __bf16 bf16x8 __attribute__((ext_vector_type(8)));
typedef float f32x4 __attribute__((ext_vector_type(4)));
typedef int i32x4 __attribute__((ext_vector_type(4)));
typedef unsigned int u32x4 __attribute__((ext_vector_type(4)));
typedef unsigned int u32x2 __attribute__((ext_vector_type(2)));
typedef unsigned short u16;
typedef unsigned long long u64;

static __device__ __forceinline__ float bf2f(u16 u) {
  unsigned int x = ((unsigned int)u) << 16;
  return __builtin_bit_cast(float, x);
}
static __device__ __forceinline__ u16 f2bf(float f) {
  unsigned int x = __builtin_bit_cast(unsigned int, f);
  unsigned int r = x + 0x7FFFu + ((x >> 16) & 1u);
  return (u16)(r >> 16);
}
static __device__ __forceinline__ signed char q8(float v) {
  float r = fminf(fmaxf(rintf(v), -127.f), 127.f);
  return (signed char)(int)r;
}

// device-coherent (L1+L2-bypassing, visible at L3) ops
static __device__ __forceinline__ void cstore16(void* p, u32x4 v) {
  asm volatile("global_store_dwordx4 %0, %1, off sc0 sc1" :: "v"(p), "v"(v) : "memory");
}
static __device__ __forceinline__ void cstore8(void* p, u64 v) {
  u32x2 d = __builtin_bit_cast(u32x2, v);
  asm volatile("global_store_dwordx2 %0, %1, off sc0 sc1" :: "v"(p), "v"(d) : "memory");
}
static __device__ __forceinline__ void flagstore4(void* p, int v) {
  asm volatile("global_store_dword %0, %1, off sc0 sc1" :: "v"(p), "v"(v) : "memory");
}
static __device__ __forceinline__ int flagload4(const void* p) {
  int v;
  asm volatile("global_load_dword %0, %1, off sc0 sc1\n\ts_waitcnt vmcnt(0)"
               : "=v"(v) : "v"(p) : "memory");
  return v;
}
// async global->LDS, 16B per lane
static __device__ __forceinline__ void gload_lds16(const void* g, void* s) {
  __builtin_amdgcn_global_load_lds(
      (const __attribute__((address_space(1))) unsigned int*)g,
      (__attribute__((address_space(3))) unsigned int*)s, 16, 0, 0);
}

// ---------------- fused prep: quant_w + embed + weight casts ----------------
__global__ __launch_bounds__(256) void k_prep(
    const float* __restrict__ decW, signed char* __restrict__ decWq,
    float* __restrict__ wscale,
    const int* __restrict__ seq, const float* __restrict__ emb,
    u16* __restrict__ xb,
    const float* __restrict__ Whhf, const float* __restrict__ Whhb,
    const float* __restrict__ Wihf, const float* __restrict__ Wihb,
    u16* __restrict__ Whh_bf, u16* __restrict__ Wih_bf)
{
  __shared__ float red[4];
  __shared__ float s_inv;
  const int bid = blockIdx.x;
  const int tid = threadIdx.x;

  if (bid < VV) {
    const int v = bid;
    const int l = tid & 63, w = tid >> 6;
    float4 x = *(const float4*)(decW + (long)v * 1024 + tid * 4);
    float m = fmaxf(fmaxf(fabsf(x.x), fabsf(x.y)), fmaxf(fabsf(x.z), fabsf(x.w)));
#pragma unroll
    for (int off = 32; off; off >>= 1) m = fmaxf(m, __shfl_xor(m, off));
    if (l == 0) red[w] = m;
    __syncthreads();
    if (tid == 0) {
      float mm = fmaxf(fmaxf(red[0], red[1]), fmaxf(red[2], red[3]));
      mm = fmaxf(mm, 1e-12f);
      s_inv = 127.f / mm;
      wscale[v] = mm / (127.f * 127.f);
    }
    __syncthreads();
    float inv = s_inv;
    char4 o;
    o.x = q8(x.x * inv); o.y = q8(x.y * inv); o.z = q8(x.z * inv); o.w = q8(x.w * inv);
    *(char4*)(decWq + (long)v * 1024 + tid * 4) = o;
  } else if (bid < VV + 4096) {
    int rb = (bid - VV) * 2 + (tid >> 7);
    int t = tid & 127;
    int v = seq[rb];
    float4 val = ((const float4*)(emb + (long)v * EE))[t];
    ushort4 o;
    o.x = f2bf(val.x); o.y = f2bf(val.y); o.z = f2bf(val.z); o.w = f2bf(val.w);
    ((ushort4*)(xb + (long)rb * EE))[t] = o;
  } else {
    int c = bid - VV - 4096;
    int tensor = c / 768;
    int i = (c % 768) * 256 + tid;
    const float4* s; ushort4* d;
    switch (tensor) {
      case 0: s = (const float4*)Whhf; d = (ushort4*)Whh_bf; break;
      case 1: s = (const float4*)Whhb; d = (ushort4*)(Whh_bf + G3 * HH); break;
      case 2: s = (const float4*)Wihf; d = (ushort4*)Wih_bf; break;
      default: s = (const float4*)Wihb; d = (ushort4*)(Wih_bf + G3 * EE); break;
    }
    float4 v = s[i];
    ushort4 o;
    o.x = f2bf(v.x); o.y = f2bf(v.y); o.z = f2bf(v.z); o.w = f2bf(v.w);
    d[i] = o;
  }
}

// ---------------- gx GEMM (both directions, blockIdx.z selects) -------------
__global__ __launch_bounds__(256) void k_gemm_gx(
    const u16* __restrict__ A, const u16* __restrict__ W0, const u16* __restrict__ W1,
    const float* __restrict__ b0, const float* __restrict__ b1, u16* __restrict__ C)
{
  __shared__ char smem[32768];
  const int tid = threadIdx.x;
  const int l = tid & 63;
  const int w = tid >> 6;
  const int wr = w >> 1, wc = w & 1;
  const long tM = (long)blockIdx.x * 128;
  const long tN = (long)blockIdx.y * 128;
  const int z = blockIdx.z;
  const u16* B = z ? W1 : W0;
  const float* bias = z ? b1 : b0;
  u16* Cz = C + (size_t)z * MROWS * G3;

  f32x4 acc[4][4];
#pragma unroll
  for (int m = 0; m < 4; m++)
#pragma unroll
    for (int n = 0; n < 4; n++) acc[m][n] = {0.f, 0.f, 0.f, 0.f};

  for (int kt = 0; kt < 8; ++kt) {
    const int k0 = kt << 6;
#pragma unroll
    for (int i = 0; i < 4; i++) {
      int cchunk = w * 4 + i;
      int c = cchunk * 64 + l;
      int row = c >> 3, k8 = c & 7;
      gload_lds16(A + (tM + row) * EE + k0 + k8 * 8, smem + cchunk * 1024);
      gload_lds16(B + (tN + row) * EE + k0 + k8 * 8, smem + 16384 + cchunk * 1024);
    }
    __syncthreads();
#pragma unroll
    for (int kk = 0; kk < 2; kk++) {
      const int kb = kk * 64 + ((l >> 4) * 16);
      bf16x8 af[4], bfr[4];
#pragma unroll
      for (int m = 0; m < 4; m++) {
        int ra = wr * 64 + m * 16 + (l & 15);
        af[m] = *(const bf16x8*)(smem + ra * 128 + kb);
      }
#pragma unroll
      for (int n = 0; n < 4; n++) {
        int rb2 = wc * 64 + n * 16 + (l & 15);
        bfr[n] = *(const bf16x8*)(smem + 16384 + rb2 * 128 + kb);
      }
#pragma unroll
      for (int m = 0; m < 4; m++)
#pragma unroll
        for (int n = 0; n < 4; n++)
          acc[m][n] = __builtin_amdgcn_mfma_f32_16x16x32_bf16(af[m], bfr[n], acc[m][n], 0, 0, 0);
    }
    __syncthreads();
  }
#pragma unroll
  for (int n = 0; n < 4; n++) {
    long col = tN + wc * 64 + n * 16 + (l & 15);
    float bv = bias[col];
#pragma unroll
    for (int m = 0; m < 4; m++) {
      long row = tM + wr * 64 + m * 16 + ((l >> 4) * 4);
#pragma unroll
      for (int r = 0; r < 4; r++)
        Cz[(row + r) * G3 + col] = f2bf(acc[m][n][r] + bv);
    }
  }
}

// ================= fused GRU + persistent decoder (R15-proven) =================
static __device__ void gru_body(
    int blk, int dir, int tid, char* lds,
    const u16* __restrict__ Whh_all,
    const float* __restrict__ bhh_f, const float* __restrict__ bhh_b,
    const u16* __restrict__ gx_all, u16* __restrict__ hsteps,
    signed char* __restrict__ catq, int* __restrict__ bar16)
{
  const int l = tid & 63, w = tid >> 6;
  const u16* Whh = Whh_all + (long)dir * G3 * HH;
  const float* bhh = dir ? bhh_b : bhh_f;
  const u16* gx = gx_all + (long)dir * MROWS * G3;

  char* Wl = lds;
  u16 (*hstage)[32] = (u16(*)[32])(lds + 96 * 1024);
  signed char (*hstageq)[32] = (signed char(*)[32])(lds + 96 * 1024 + 4096);

  for (int c = tid; c < 6144; c += 256) {
    int lr = c >> 6;
    int k8 = c & 63;
    int gr = (lr >> 5) * HH + blk * 32 + (lr & 31);
    uint4 v = *(const uint4*)(Whh + (long)gr * HH + k8 * 8);
    *(uint4*)(Wl + lr * 1024 + ((k8 * 16) ^ ((lr & 7) << 4))) = v;
  }
  float bh[6];
#pragma unroll
  for (int n = 0; n < 6; n++) {
    int c = n * 16 + (l & 15);
    bh[n] = bhh[(c >> 5) * HH + blk * 32 + (c & 31)];
  }
  float hreg[4][2] = {};
  __syncthreads();

  const int lrow = w * 16 + ((l >> 4) * 4);
  const int srow = tid >> 2, schunk = tid & 3;

  u16 gxn[3][4][2];
  {
    const int lpos0 = dir ? (LL - 1) : 0;
#pragma unroll
    for (int r = 0; r < 4; r++) {
      const u16* gxr = gx + ((long)lpos0 * BB + (lrow + r)) * G3 + blk * 32;
#pragma unroll
      for (int g = 0; g < 3; g++)
#pragma unroll
        for (int p = 0; p < 2; p++)
          gxn[g][r][p] = gxr[g * HH + p * 16 + (l & 15)];
    }
  }

  for (int t = 0; t < LL; ++t) {
    const int lpos = dir ? (LL - 1 - t) : t;
    const u16* hsrc = hsteps + ((size_t)t * 2 + dir) * BB * HH;

    u16 gxv[3][4][2];
#pragma unroll
    for (int g = 0; g < 3; g++)
#pragma unroll
      for (int r = 0; r < 4; r++)
#pragma unroll
        for (int p = 0; p < 2; p++) gxv[g][r][p] = gxn[g][r][p];

    bf16x8 af[16];
    {
      const u16* hrow = hsrc + (w * 16 + (l & 15)) * HH + ((l >> 4) * 8);
#pragma unroll
      for (int kc = 0; kc < 16; kc++) af[kc] = *(const bf16x8*)(hrow + kc * 32);
    }

    f32x4 acc[6];
#pragma unroll
    for (int n = 0; n < 6; n++) acc[n] = {0.f, 0.f, 0.f, 0.f};
#pragma unroll
    for (int kc = 0; kc < 16; kc++) {
      const int kb = kc * 64 + ((l >> 4) * 16);
#pragma unroll
      for (int n = 0; n < 6; n++) {
        int lr = n * 16 + (l & 15);
        bf16x8 bfr = *(const bf16x8*)(Wl + lr * 1024 + (kb ^ ((l & 7) << 4)));
        acc[n] = __builtin_amdgcn_mfma_f32_16x16x32_bf16(af[kc], bfr, acc[n], 0, 0, 0);
      }
    }

#pragma unroll
    for (int r = 0; r < 4; r++) {
#pragma unroll
      for (int p = 0; p < 2; p++) {
        float ghr = acc[0 + p][r] + bh[0 + p];
        float ghz = acc[2 + p][r] + bh[2 + p];
        float ghn = acc[4 + p][r] + bh[4 + p];
        float xr = bf2f(gxv[0][r][p]);
        float xz = bf2f(gxv[1][r][p]);
        float xn = bf2f(gxv[2][r][p]);
        float ar = fminf(fmaxf(xr + ghr, -30.f), 30.f);
        float az = fminf(fmaxf(xz + ghz, -30.f), 30.f);
        float rg = 1.f / (1.f + __expf(-ar));
        float zg = 1.f / (1.f + __expf(-az));
        float an = fminf(fmaxf(xn + rg * ghn, -30.f), 30.f);
        float e2 = __expf(-2.f * an);
        float ng = (1.f - e2) / (1.f + e2);
        float hn = (1.f - zg) * ng + zg * hreg[r][p];
        hreg[r][p] = hn;
        hstage[lrow + r][p * 16 + (l & 15)] = f2bf(hn);
        hstageq[lrow + r][p * 16 + (l & 15)] = q8(hn * 127.f);
      }
    }
    __syncthreads();

    u32x4 hv = *(const u32x4*)&hstage[srow][schunk * 8];
    u64 hq = *(const u64*)&hstageq[srow][schunk * 8];
    if (t < LL - 1)
      cstore16(hsteps + ((size_t)(t + 1) * 2 + dir) * BB * HH + srow * HH + blk * 32 + schunk * 8, hv);
    if (dir == 0) {
      if (lpos < LL - 2)
        cstore8(catq + ((long)lpos * BB + srow) * D2H + blk * 32 + schunk * 8, hq);
    } else {
      if (lpos >= 2)
        cstore8(catq + ((long)(lpos - 2) * BB + srow) * D2H + HH + blk * 32 + schunk * 8, hq);
    }
    if (t < LL - 1) {
      asm volatile("s_waitcnt vmcnt(0)" ::: "memory");
      __syncthreads();
      if (tid == 0)
        flagstore4(&bar16[((dir * LL + t) * 16 + blk) * FP], 1);
      {
        const int lposn = dir ? (LL - 2 - t) : (t + 1);
#pragma unroll
        for (int r = 0; r < 4; r++) {
          const u16* gxr = gx + ((long)lposn * BB + (lrow + r)) * G3 + blk * 32;
#pragma unroll
          for (int g = 0; g < 3; g++)
#pragma unroll
            for (int p = 0; p < 2; p++)
              gxn[g][r][p] = gxr[g * HH + p * 16 + (l & 15)];
        }
      }
      const int* flg = bar16 + (dir * LL + t) * 16 * FP;
      for (;;) {
        int v = 1;
        if (l < 16) v = flagload4(&flg[l * FP]);
        if (__all(v != 0)) break;
      }
      __builtin_amdgcn_sched_barrier(0);
    }
  }
}

static __device__ void dec_body(
    int tid, char* smem, int* tk_sh,
    const signed char* __restrict__ A, const signed char* __restrict__ B,
    const float* __restrict__ wscale, const float* __restrict__ bias,
    void* __restrict__ Cv, int outbf,
    int* __restrict__ ticket, const int* __restrict__ bar16)
{
  const int l = tid & 63;
  const int w = tid >> 6;
  const int wr = w >> 1, wc = w & 1;

  for (;;) {
    if (tid == 0)
      *tk_sh = __hip_atomic_fetch_add(ticket, 1, __ATOMIC_RELAXED, __HIP_MEMORY_SCOPE_AGENT);
    __syncthreads();
    const int n = *tk_sh;
    __syncthreads();
    if (n >= DECQ) return;
    const int k = n / NTILE_N, j = n % NTILE_N;
    const int mi = (k & 1) ? (31 + ((k + 1) >> 1)) : (31 - (k >> 1));
    const long tM = (long)mi * 128;
    const long tN = (long)j * 128;

    {
      const int tf = 2 * mi + 1;
      const int tb = 125 - 2 * mi;
      const int* fp = (l < 16)
          ? bar16 + ((0 * LL + tf) * 16 + l) * FP
          : bar16 + ((1 * LL + tb) * 16 + (l & 15)) * FP;
      for (;;) {
        int v = 1;
        if (l < 32) v = flagload4(fp);
        if (__all(v != 0)) break;
      }
    }

    i32x4 acc[4][4];
#pragma unroll
    for (int m = 0; m < 4; m++)
#pragma unroll
      for (int nn = 0; nn < 4; nn++) acc[m][nn] = {0, 0, 0, 0};

    for (int kt = 0; kt < 8; ++kt) {
      const int k0 = kt << 7;
#pragma unroll
      for (int i = 0; i < 4; i++) {
        int jj = w * 4 + i;
        int row = jj * 8 + (l >> 3);
        int k16 = l & 7;
        gload_lds16(A + (tM + row) * 1024 + k0 + k16 * 16, smem + jj * 1024);
        gload_lds16(B + (tN + row) * 1024 + k0 + k16 * 16, smem + 16384 + jj * 1024);
      }
      __syncthreads();
#pragma unroll
      for (int ks = 0; ks < 2; ks++) {
        const int kb = ks * 64 + ((l >> 4) * 16);
        i32x4 af[4], bfr[4];
#pragma unroll
        for (int m = 0; m < 4; m++) {
          int ra = wr * 64 + m * 16 + (l & 15);
          af[m] = *(const i32x4*)(smem + ra * 128 + kb);
        }
#pragma unroll
        for (int nn = 0; nn < 4; nn++) {
          int rb2 = wc * 64 + nn * 16 + (l & 15);
          bfr[nn] = *(const i32x4*)(smem + 16384 + rb2 * 128 + kb);
        }
#pragma unroll
        for (int m = 0; m < 4; m++)
#pragma unroll
          for (int nn = 0; nn < 4; nn++)
            acc[m][nn] = __builtin_amdgcn_mfma_i32_16x16x64_i8(af[m], bfr[nn], acc[m][nn], 0, 0, 0);
      }
      __syncthreads();
    }
#pragma unroll
    for (int nn = 0; nn < 4; nn++) {
      long col = tN + wc * 64 + nn * 16 + (l & 15);
      if (col < VV) {
        float sc = wscale[col];
        float bv = bias[col];
#pragma unroll
        for (int m = 0; m < 4; m++) {
          long row = tM + wr * 64 + m * 16 + ((l >> 4) * 4);
#pragma unroll
          for (int r = 0; r < 4; r++) {
            float vv = (float)acc[m][nn][r] * sc + bv;
            if (outbf) ((u16*)Cv)[(row + r) * NPAD + col] = f2bf(vv);
            else       ((float*)Cv)[(row + r) * VV + col] = vv;
          }
        }
      }
    }
  }
}

__global__ __launch_bounds__(256) void k_fused(
    const u16* __restrict__ Whh_all,
    const float* __restrict__ bhh_f, const float* __restrict__ bhh_b,
    const u16* __restrict__ gx_all, u16* __restrict__ hsteps,
    signed char* __restrict__ catq, int* __restrict__ bar16,
    const signed char* __restrict__ decWq, const float* __restrict__ wscale,
    const float* __restrict__ decb, void* __restrict__ Cv, int outbf,
    int* __restrict__ ticket)
{
  __shared__ __align__(16) char lds[104448];
  __shared__ int tk_sh;
  const int bid = blockIdx.x;
  const int tid = threadIdx.x;
  if (bid < 32) {
    gru_body(bid >> 1, bid & 1, tid, lds, Whh_all, bhh_f, bhh_b, gx_all,
             hsteps, catq, bar16);
  } else {
    dec_body(tid, lds, &tk_sh, catq, decWq, wscale, decb, Cv, outbf, ticket, bar16);
  }
}

// ---------------- log-softmax, f32 in-place (fallback) ----------------
__global__ __launch_bounds__(256) void k_lsm(float* __restrict__ out) {
  const long row = blockIdx.x;
  float* p = out + row * VV;
  const int tid = threadIdx.x;
  const int l = tid & 63, w = tid >> 6;
  __shared__ float red[8];

  float4 v[10];
  float m = -1e30f;
#pragma unroll
  for (int j = 0; j < 10; j++) {
    int idx = j * 256 + tid;
    if (idx < 2500) {
      v[j] = *(float4*)(p + idx * 4);
      m = fmaxf(m, fmaxf(fmaxf(v[j].x, v[j].y), fmaxf(v[j].z, v[j].w)));
    }
  }
#pragma unroll
  for (int off = 32; off; off >>= 1) m = fmaxf(m, __shfl_xor(m, off));
  if (l == 0) red[w] = m;
  __syncthreads();
  m = fmaxf(fmaxf(red[0], red[1]), fmaxf(red[2], red[3]));

  float s = 0.f;
#pragma unroll
  for (int j = 0; j < 10; j++) {
    int idx = j * 256 + tid;
    if (idx < 2500) {
      s += __expf(v[j].x - m) + __expf(v[j].y - m) + __expf(v[j].z - m) + __expf(v[j].w - m);
    }
  }
#pragma unroll
  for (int off = 32; off; off >>= 1) s += __shfl_xor(s, off);
  if (l == 0) red[4 + w] = s;
  __syncthreads();
  s = red[4] + red[5] + red[6] + red[7];
  float lse = m + logf(s);

#pragma unroll
  for (int j = 0; j < 10; j++) {
    int idx = j * 256 + tid;
    if (idx < 2500) {
      float4 o;
      o.x = v[j].x - lse; o.y = v[j].y - lse; o.z = v[j].z - lse; o.w = v[j].w - lse;
      *(float4*)(p + idx * 4) = o;
    }
  }
}

// ---------------- log-softmax, bf16 logits -> f32 out (high occupancy) -------
__global__ __launch_bounds__(256) void k_lsm_b(const u16* __restrict__ lg,
                                               float* __restrict__ out) {
  const long row = blockIdx.x;
  const u16* p = lg + row * NPAD;
  float* q = out + row * VV;
  const int tid = threadIdx.x;
  const int l = tid & 63, w = tid >> 6;
  __shared__ float red[8];

  float v[5][8];
  float m = -1e30f;
#pragma unroll
  for (int j = 0; j < 5; j++) {
    int idx8 = j * 256 + tid;
    if (idx8 < 1250) {
      u32x4 u = *(const u32x4*)(p + idx8 * 8);
#pragma unroll
      for (int e = 0; e < 4; e++) {
        v[j][2 * e]     = bf2f((u16)(u[e] & 0xffffu));
        v[j][2 * e + 1] = bf2f((u16)(u[e] >> 16));
      }
#pragma unroll
      for (int e = 0; e < 8; e++) m = fmaxf(m, v[j][e]);
    }
  }
#pragma unroll
  for (int off = 32; off; off >>= 1) m = fmaxf(m, __shfl_xor(m, off));
  if (l == 0) red[w] = m;
  __syncthreads();
  m = fmaxf(fmaxf(red[0], red[1]), fmaxf(red[2], red[3]));

  float s = 0.f;
#pragma unroll
  for (int j = 0; j < 5; j++) {
    int idx8 = j * 256 + tid;
    if (idx8 < 1250) {
#pragma unroll
      for (int e = 0; e < 8; e++) s += __expf(v[j][e] - m);
    }
  }
#pragma unroll
  for (int off = 32; off; off >>= 1) s += __shfl_xor(s, off);
  if (l == 0) red[4 + w] = s;
  __syncthreads();
  s = red[4] + red[5] + red[6] + red[7];
  float lse = m + logf(s);

#pragma unroll
  for (int j = 0; j < 5; j++) {
    int idx8 = j * 256 + tid;
    if (idx8 < 1250) {
      float4 a, b;
      a.x = v[j][0] - lse; a.y = v[j][1] - lse; a.z = v[j][2] - lse; a.w = v[j][3] - lse;
      b.x = v[j][4] - lse; b.y = v[j][5] - lse; b.z = v[j][6] - lse; b.w = v[j][7] - lse;
      *(float4*)(q + idx8 * 8) = a;
      *(float4*)(q + idx8 * 8 + 4) = b;
    }
  }
}

// ---------------- launch ----------------
extern "C" void kernel_launch(void* const* d_in, const int* in_sizes, int n_in,
                              void* d_out, int out_size, void* d_ws, size_t ws_size,
                              hipStream_t stream) {
  const int*   seq  = (const int*)d_in[0];
  const float* emb  = (const float*)d_in[2];
  const float* Wihf = (const float*)d_in[3];
  const float* Whhf = (const float*)d_in[4];
  const float* bihf = (const float*)d_in[5];
  const float* bhhf = (const float*)d_in[6];
  const float* Wihb = (const float*)d_in[7];
  const float* Whhb = (const float*)d_in[8];
  const float* bihb = (const float*)d_in[9];
  const float* bhhb = (const float*)d_in[10];
  const float* decW = (const float*)d_in[11];
  const float* decb = (const float*)d_in[12];

  char* ws = (char*)d_ws;
  size_t off = 0;
  u16* Whh_bf = (u16*)(ws + off); off += (size_t)2 * G3 * HH * 2;
  u16* Wih_bf = (u16*)(ws + off); off += (size_t)2 * G3 * EE * 2;
  signed char* decWq = (signed char*)(ws + off); off += (size_t)NPAD * 1024;
  float* wscale = (float*)(ws + off); off += (size_t)NPAD * 4;
  u16* xb = (u16*)(ws + off); off += (size_t)MROWS * EE * 2;
  u16* gxb = (u16*)(ws + off); off += (size_t)2 * MROWS * G3 * 2;
  signed char* catq = (signed char*)(ws + off); off += (size_t)DM * D2H;
  u16* hsteps = (u16*)(ws + off); off += (size_t)(LL + 1) * 2 * BB * HH * 2;
  int* bar16 = (int*)(ws + off); off += (size_t)2 * LL * 16 * FP * 4;
  int* ticket = (int*)(ws + off); off += 64;
  u16* logitsb = (u16*)(ws + off);
  const size_t logits_bytes = (size_t)DM * NPAD * 2;
  const bool use_bf16_logits = (ws_size >= off + logits_bytes);

  (void)hipMemsetAsync(hsteps, 0, (size_t)2 * BB * HH * 2, stream);
  (void)hipMemsetAsync(bar16, 0, (size_t)2 * LL * 16 * FP * 4 + 64, stream);

  k_prep<<<dim3(VV + 4096 + 3072), 256, 0, stream>>>(
      decW, decWq, wscale, seq, emb, xb,
      Whhf, Whhb, Wihf, Wihb, Whh_bf, Wih_bf);

  k_gemm_gx<<<dim3(64, 12, 2), 256, 0, stream>>>(xb, Wih_bf, Wih_bf + G3 * EE,
                                                 bihf, bihb, gxb);

  void* Cv = use_bf16_logits ? (void*)logitsb : (void*)d_out;
  k_fused<<<dim3(256), 256, 0, stream>>>(Whh_bf, bhhf, bhhb, gxb, hsteps, catq,
                                         bar16, decWq, wscale, decb, Cv,
                                         use_bf16_logits ? 1 : 0, ticket);

  if (use_bf16_logits) k_lsm_b<<<DM, 256, 0, stream>>>(logitsb, (float*)d_out);
  else                 k_lsm<<<DM, 256, 0, stream>>>((float*)d_out);
}